// Round 6
// baseline (121.474 us; speedup 1.0000x reference)
//
#include <hip/hip_runtime.h>

typedef _Float16 f16x8 __attribute__((ext_vector_type(8)));
typedef float f32x16 __attribute__((ext_vector_type(16)));

#define V_TOTAL 8192
#define C_DIM   64
#define N_TOK   32768
#define VSPLIT  8
#define VSEG    (V_TOTAL / VSPLIT)   // 1024
#define CHUNKS  (VSEG / 32)          // 32
#define INV2048 4.8828125e-4f

typedef const __attribute__((address_space(1))) _Float16 glb_f16;
typedef __attribute__((address_space(3))) _Float16 lds_f16;

// ws float offsets:
//   cp      f16[1048576]  @ 0        (2 MiB) packed split codes
//           offset = cvg*4096 + term*2048 + q*256 + c*8   (k = q*8+j, cvg = global chunk)
//   keys    u64[32768]    @ 524288   (256 KiB) packed (sortable_sim, 8191-idx)
//   counts  int[8192]     @ 589824
//   blocksq f32[256]      @ 598016

__device__ __forceinline__ unsigned long long packkey(float s, int idx) {
    unsigned u = __float_as_uint(s);
    unsigned k = u ^ ((unsigned)(((int)u) >> 31) | 0x80000000u);
    return ((unsigned long long)k << 32) | (unsigned)(8191 - idx);
}

__global__ __launch_bounds__(256)
void k_prep(const float* __restrict__ w, _Float16* __restrict__ cp,
            unsigned long long* __restrict__ keys, int* __restrict__ counts) {
    int v = blockIdx.x * 256 + threadIdx.x;   // one code per thread
    counts[v] = 0;
#pragma unroll
    for (int i = 0; i < 4; ++i) keys[v * 4 + i] = 0ull;   // 8192*4 = 32768
    const float4* row = (const float4*)(w + v * C_DIM);
    float4 r[16];
    float s = 0.f;
#pragma unroll
    for (int i = 0; i < 16; ++i) {
        r[i] = row[i];
        s += r[i].x * r[i].x + r[i].y * r[i].y + r[i].z * r[i].z + r[i].w * r[i].w;
    }
    float inv = 1.0f / fmaxf(sqrtf(s), 1e-12f);
    const float* rs = (const float*)r;
    const int cv = v >> 5, c = v & 31;
#pragma unroll
    for (int q = 0; q < 8; ++q) {
        f16x8 hi, lo;
#pragma unroll
        for (int j = 0; j < 8; ++j) {
            float x = rs[q * 8 + j] * inv;
            _Float16 h = (_Float16)x;
            hi[j] = h;
            lo[j] = (_Float16)((x - (float)h) * 2048.0f);
        }
        *(f16x8*)(cp + cv * 4096 +        q * 256 + c * 8) = hi;
        *(f16x8*)(cp + cv * 4096 + 2048 + q * 256 + c * 8) = lo;
    }
}

// 4 waves/block; each wave owns 32 tokens; block shares staged code chunks via LDS.
// 4-deep chunk pipeline: counted vmcnt keeps 4 loads in flight across barriers.
__global__ __launch_bounds__(256, 4)
void k_argmax(const float* __restrict__ f, const _Float16* __restrict__ cp,
              unsigned long long* __restrict__ keys) {
    __shared__ __align__(16) _Float16 lds[4][4096];   // 4 x 8 KiB chunk buffers

    const int tid  = threadIdx.x;
    const int lane = tid & 63;
    const int wid  = tid >> 6;
    const int c31  = lane & 31;
    const int g    = lane >> 5;
    const int seg  = blockIdx.y;          // 0..VSPLIT-1
    const int t0   = blockIdx.x * 128 + wid * 32;   // this wave's 32 tokens

    // ---- B (token) fragments, register-resident: 8 x f16x8 = 32 VGPR ----
    f16x8 bh[4], bl[4];
    {
        const int T = t0 + c31;
        const float* fb = f + (T >> 10) * 65536 + (T & 1023);
#pragma unroll
        for (int ks = 0; ks < 4; ++ks) {
#pragma unroll
            for (int j = 0; j < 8; ++j) {
                float v = fb[(ks * 16 + g * 8 + j) * 1024];
                _Float16 h = (_Float16)v;
                bh[ks][j] = h;
                bl[ks][j] = (_Float16)((v - (float)h) * 2048.0f);
            }
        }
    }

    const _Float16* seg_cp = cp + (size_t)seg * (CHUNKS * 4096);

    // stage chunk cv into lds[cv&3]: 8 KiB, each wave covers 2 KiB linearly
    auto stage = [&](int cv) {
        const _Float16* src = seg_cp + cv * 4096 + wid * 1024 + lane * 8;
        _Float16* dst = &lds[cv & 3][wid * 1024];    // wave-uniform base
        __builtin_amdgcn_global_load_lds((glb_f16*)src,       (lds_f16*)dst,       16, 0, 0);
        __builtin_amdgcn_global_load_lds((glb_f16*)(src+512), (lds_f16*)(dst+512), 16, 0, 0);
    };

    const f32x16 zacc = {0.f,0.f,0.f,0.f,0.f,0.f,0.f,0.f,0.f,0.f,0.f,0.f,0.f,0.f,0.f,0.f};

    float best = -3.4e38f;
    int   bidx = 0;    // holds code' (without +4g), added at end

    stage(0);
    stage(1);
    stage(2);

#pragma unroll 1
    for (int cv = 0; cv < CHUNKS; ++cv) {
        // drain exactly chunk cv's 2 loads; keep later prefetches in flight
        if (cv < CHUNKS - 2)       asm volatile("s_waitcnt vmcnt(4)" ::: "memory");
        else if (cv == CHUNKS - 2) asm volatile("s_waitcnt vmcnt(2)" ::: "memory");
        else                       asm volatile("s_waitcnt vmcnt(0)" ::: "memory");
        __builtin_amdgcn_s_barrier();      // all waves: buf[cv&3] staged, buf[(cv-1)&3] consumed
        if (cv + 3 < CHUNKS) stage(cv + 3);

        const _Float16* base = &lds[cv & 3][g * 256 + c31 * 8];
        f32x16 am, ac;
        {
            f16x8 AH = *(const f16x8*)(base);
            f16x8 AL = *(const f16x8*)(base + 2048);
            am = __builtin_amdgcn_mfma_f32_32x32x16_f16(AH, bh[0], zacc, 0, 0, 0);
            ac = __builtin_amdgcn_mfma_f32_32x32x16_f16(AH, bl[0], zacc, 0, 0, 0);
            ac = __builtin_amdgcn_mfma_f32_32x32x16_f16(AL, bh[0], ac, 0, 0, 0);
        }
#pragma unroll
        for (int ks = 1; ks < 4; ++ks) {
            f16x8 AH = *(const f16x8*)(base + ks * 512);
            f16x8 AL = *(const f16x8*)(base + 2048 + ks * 512);
            am = __builtin_amdgcn_mfma_f32_32x32x16_f16(AH, bh[ks], am, 0, 0, 0);
            ac = __builtin_amdgcn_mfma_f32_32x32x16_f16(AH, bl[ks], ac, 0, 0, 0);
            ac = __builtin_amdgcn_mfma_f32_32x32x16_f16(AL, bh[ks], ac, 0, 0, 0);
        }

        const int codebase = seg * VSEG + cv * 32;   // wave-uniform (SGPR)
#pragma unroll
        for (int r = 0; r < 16; ++r) {
            const int codeq = codebase + (r & 3) + 8 * (r >> 2);
            float s = fmaf(ac[r], INV2048, am[r]);
            bool u = s > best;
            best = u ? s : best;
            bidx = u ? codeq : bidx;
        }
        // no trailing barrier: next iteration's barrier provides the WAR guard
    }

    bidx += 4 * g;
    {
        float ov = __shfl_xor(best, 32);
        int   oi = __shfl_xor(bidx, 32);
        if (ov > best || (ov == best && oi < bidx)) { best = ov; bidx = oi; }
    }
    if (lane < 32) {
        atomicMax(&keys[t0 + c31], packkey(best, bidx));
    }
}

__global__ __launch_bounds__(128)
void k_finalize(const float* __restrict__ f, const float* __restrict__ w,
                const unsigned long long* __restrict__ keys,
                int* __restrict__ counts, float* __restrict__ blocksq,
                float* __restrict__ out) {
    const int tid = threadIdx.x;
    const int t   = blockIdx.x * 128 + tid;   // token id

    const int bi = 8191 - (int)(unsigned)(keys[t] & 0xFFFFFFFFull);
    atomicAdd(&counts[bi], 1);

    float4 cr[16];
    const float4* crow = (const float4*)(w + bi * C_DIM);
#pragma unroll
    for (int i = 0; i < 16; ++i) cr[i] = crow[i];
    const float* crs = (const float*)cr;

    const int bb = t >> 10;
    const int hw = t & 1023;
    const float* fb = f + bb * 65536 + hw;
    float*       ob = out + bb * 65536 + hw;

    float s = 0.f;
#pragma unroll
    for (int c = 0; c < C_DIM; ++c) {
        float fv = fb[c * 1024];
        float fh = crs[c];
        float d  = fh - fv;
        s += d * d;
        ob[c * 1024] = fv + d;   // f + sg(fhat - f)
    }

    __shared__ float red[128];
    red[tid] = s;
    __syncthreads();
    for (int st = 64; st > 0; st >>= 1) {
        if (tid < st) red[tid] += red[tid + st];
        __syncthreads();
    }
    if (tid == 0) blocksq[blockIdx.x] = red[0];
}

__global__ __launch_bounds__(256)
void k_stats(const int* __restrict__ counts, const float* __restrict__ blocksq,
             float* __restrict__ out) {
    __shared__ float redf[256];
    __shared__ int   redi[256];
    const int tid = threadIdx.x;
    int used = 0;
    for (int v = tid; v < V_TOTAL; v += 256) used += (counts[v] > 0) ? 1 : 0;
    redi[tid] = used;
    redf[tid] = blocksq[tid];
    __syncthreads();
    for (int st = 128; st > 0; st >>= 1) {
        if (tid < st) { redi[tid] += redi[tid + st]; redf[tid] += redf[tid + st]; }
        __syncthreads();
    }
    if (tid == 0) {
        float mse = redf[0] / 2097152.0f;
        out[2097152] = 0.25f * mse + mse;   // BETA*mean + mean
        out[2097153] = 0.0f;                // entropy_loss
        out[2097154] = 100.0f * (float)redi[0] / 8192.0f;  // vocab_usage
    }
}

extern "C" void kernel_launch(void* const* d_in, const int* in_sizes, int n_in,
                              void* d_out, int out_size, void* d_ws, size_t ws_size,
                              hipStream_t stream) {
    const float* f = (const float*)d_in[0];
    const float* w = (const float*)d_in[1];
    float* out = (float*)d_out;
    float* ws  = (float*)d_ws;

    _Float16*           cp      = (_Float16*)ws;
    unsigned long long* keys    = (unsigned long long*)(ws + 524288);
    int*                counts  = (int*)(ws + 589824);
    float*              blocksq = ws + 598016;

    hipLaunchKernelGGL(k_prep, dim3(32), dim3(256), 0, stream, w, cp, keys, counts);
    hipLaunchKernelGGL(k_argmax, dim3(N_TOK / 128, VSPLIT), dim3(256), 0, stream,
                       f, cp, keys);
    hipLaunchKernelGGL(k_finalize, dim3(N_TOK / 128), dim3(128), 0, stream,
                       f, w, keys, counts, blocksq, out);
    hipLaunchKernelGGL(k_stats, dim3(1), dim3(256), 0, stream,
                       counts, blocksq, out);
}